// Round 1
// 327.911 us; speedup vs baseline: 1.0691x; 1.0691x over previous
//
#include <hip/hip_runtime.h>

// FavorAttention (Performer FAVOR+) — B=4,H=8,D=64,N=8192,M=256, fp32 in/out.
// R3: occupancy push. favor_out LDS aliased (QT/dred/ot inside PHT region,
// 50688->37376 B => 4 blocks/CU); diag_k fused into favor_kmax (favor_diag
// deleted); stab reduction folded into favor_kv (favor_stab deleted).

typedef short s16x8 __attribute__((ext_vector_type(8)));
typedef float f32x4 __attribute__((ext_vector_type(4)));

#define Dv 64
#define Nv 8192
#define Mv 256
#define BHv 32
#define SPL 16
#define NSPL (Nv / SPL)   // 512
#define NCH (NSPL / 64)   // 8

#define DNRM 0.3535533905932738f   // 64^-0.25
#define EPSV 1e-6f

// ws layout (float offsets)
#define OFF_DIAGK 0
#define OFF_MAXP (BHv * Nv)
#define OFF_STAB (OFF_MAXP + BHv * SPL)
#define OFF_KNP (OFF_STAB + BHv)                 // [32][16][256]
#define OFF_KNF (OFF_KNP + BHv * SPL * Mv)       // [32][256]
#define OFF_KVP (OFF_KNF + BHv * Mv)             // [32][16][256][64] fp32
#define OFF_KVT (OFF_KVP + BHv * SPL * Mv * Dv)  // [32][64][256] bf16

__device__ __forceinline__ unsigned short f2b(float x) {
    return __builtin_bit_cast(unsigned short, (__bf16)x);
}

__device__ __forceinline__ s16x8 load_pfrag(const float* __restrict__ proj, int m,
                                            int kc, int q) {
    const float* p = proj + m * 64 + kc * 32 + q * 8;
    s16x8 r;
#pragma unroll
    for (int j = 0; j < 8; ++j) r[j] = (short)f2b(p[j]);
    return r;
}

// ---------------------------------------------------------------------------
// kmax: global max of raw u = P·K (same bf16 products as favor_kv).
// R3: also computes diag_k from the fp32 staged values (favor_diag deleted).
__global__ __launch_bounds__(256, 2) void favor_kmax(const float* __restrict__ key,
                                                     const float* __restrict__ proj,
                                                     float* __restrict__ ws) {
    __shared__ __align__(16) unsigned short KT[64][72];  // [n][d] bf16
    __shared__ float dred[16][64];                       // diag partials [g][n]
    __shared__ float red[4];
    const int tid = threadIdx.x;
    const int w = tid >> 6, l = tid & 63, c = l & 15, q = l >> 4;
    const int g = tid >> 4, cs = tid & 15;  // staging coords
    const int s = blockIdx.x, bh = blockIdx.y;
    const float* kp = key + (size_t)bh * Dv * Nv;
    float* dgw = ws + OFF_DIAGK + bh * Nv;

    s16x8 P[4][2];
#pragma unroll
    for (int mt = 0; mt < 4; ++mt)
#pragma unroll
        for (int kc = 0; kc < 2; ++kc)
            P[mt][kc] = load_pfrag(proj, (4 * w + mt) * 16 + c, kc, q);

    float vmax = -3.4e38f;
    for (int ch = 0; ch < NCH; ++ch) {
        const int n0 = s * NSPL + ch * 64;
        if (ch) __syncthreads();
        // stage: thread loads rows 4g..4g+3, cols 4cs..4cs+3 -> b64 transposed
        float4 kk[4];
#pragma unroll
        for (int di = 0; di < 4; ++di)
            kk[di] = *(const float4*)&kp[(4 * g + di) * Nv + n0 + 4 * cs];
#pragma unroll
        for (int j = 0; j < 4; ++j) {
            const float v0 = ((const float*)&kk[0])[j];
            const float v1 = ((const float*)&kk[1])[j];
            const float v2 = ((const float*)&kk[2])[j];
            const float v3 = ((const float*)&kk[3])[j];
            *(short4*)&KT[4 * cs + j][4 * g] =
                make_short4((short)f2b(v0), (short)f2b(v1), (short)f2b(v2),
                            (short)f2b(v3));
            dred[g][4 * cs + j] = (v0 * v0 + v1 * v1) + (v2 * v2 + v3 * v3);
        }
        __syncthreads();
        if (tid < 64) {
            float dsum = 0.f;
#pragma unroll
            for (int gg = 0; gg < 16; ++gg) dsum += dred[gg][tid];
            dgw[n0 + tid] = dsum * 0.0625f;
        }
#pragma unroll
        for (int nt = 0; nt < 4; ++nt) {
            const s16x8 a0 = *(const s16x8*)&KT[nt * 16 + c][q * 8];
            const s16x8 a1 = *(const s16x8*)&KT[nt * 16 + c][32 + q * 8];
#pragma unroll
            for (int mt = 0; mt < 4; ++mt) {
                f32x4 u = {0.f, 0.f, 0.f, 0.f};
                u = __builtin_amdgcn_mfma_f32_16x16x32_bf16(a0, P[mt][0], u, 0, 0, 0);
                u = __builtin_amdgcn_mfma_f32_16x16x32_bf16(a1, P[mt][1], u, 0, 0, 0);
                vmax = fmaxf(vmax, fmaxf(fmaxf(u[0], u[1]), fmaxf(u[2], u[3])));
            }
        }
    }
#pragma unroll
    for (int off = 1; off < 64; off <<= 1)
        vmax = fmaxf(vmax, __shfl_xor(vmax, off, 64));
    if (l == 0) red[w] = vmax;
    __syncthreads();
    if (tid == 0)
        ws[OFF_MAXP + bh * SPL + s] =
            fmaxf(fmaxf(red[0], red[1]), fmaxf(red[2], red[3]));
}

// ---------------------------------------------------------------------------
// kv: U^T = K^T·P^T → exp → phi (wave-private LDS, kc-split) → kv += phi·V^T.
// R3: stab computed inline from the 16 split maxima (favor_stab deleted).
__global__ __launch_bounds__(256, 2) void favor_kv(const float* __restrict__ key,
                                                   const float* __restrict__ value,
                                                   const float* __restrict__ proj,
                                                   float* __restrict__ ws) {
    __shared__ __align__(16) unsigned short KT[64][72];   // [n][d]
    __shared__ __align__(16) unsigned short VL[64][72];   // [d][n]
    __shared__ __align__(16) unsigned short PH[256][40];  // [m][32n half] phi
    const int tid = threadIdx.x;
    const int w = tid >> 6, l = tid & 63, c = l & 15, q = l >> 4;
    const int g = tid >> 4, cs = tid & 15;
    const int s = blockIdx.x, bh = blockIdx.y;
    const float* kp = key + (size_t)bh * Dv * Nv;
    const float* vp = value + (size_t)bh * Dv * Nv;
    const float* dgp = ws + OFF_DIAGK + bh * Nv;

    float stab;
    {
        const float* mp = ws + OFF_MAXP + bh * SPL;
        float r = mp[0];
#pragma unroll
        for (int s2 = 1; s2 < SPL; ++s2) r = fmaxf(r, mp[s2]);
        stab = r * DNRM;
    }

    s16x8 P[4][2];
#pragma unroll
    for (int mt = 0; mt < 4; ++mt)
#pragma unroll
        for (int kc = 0; kc < 2; ++kc)
            P[mt][kc] = load_pfrag(proj, (4 * w + mt) * 16 + c, kc, q);

    f32x4 kva[4][4];
#pragma unroll
    for (int mt = 0; mt < 4; ++mt)
#pragma unroll
        for (int dt = 0; dt < 4; ++dt) kva[mt][dt] = (f32x4){0.f, 0.f, 0.f, 0.f};
    float kn[4] = {0.f, 0.f, 0.f, 0.f};

    for (int ch = 0; ch < NCH; ++ch) {
        const int n0 = s * NSPL + ch * 64;
        if (ch) __syncthreads();
        {
            float4 kk[4], vv[4];
#pragma unroll
            for (int di = 0; di < 4; ++di) {
                kk[di] = *(const float4*)&kp[(4 * g + di) * Nv + n0 + 4 * cs];
                vv[di] = *(const float4*)&vp[(4 * g + di) * Nv + n0 + 4 * cs];
            }
#pragma unroll
            for (int j = 0; j < 4; ++j)
                *(short4*)&KT[4 * cs + j][4 * g] = make_short4(
                    (short)f2b(((const float*)&kk[0])[j]),
                    (short)f2b(((const float*)&kk[1])[j]),
                    (short)f2b(((const float*)&kk[2])[j]),
                    (short)f2b(((const float*)&kk[3])[j]));
#pragma unroll
            for (int di = 0; di < 4; ++di)
                *(short4*)&VL[4 * g + di][4 * cs] = make_short4(
                    (short)f2b(vv[di].x), (short)f2b(vv[di].y),
                    (short)f2b(vv[di].z), (short)f2b(vv[di].w));
        }
        __syncthreads();
#pragma unroll
        for (int h = 0; h < 2; ++h) {
            // GEMM1 on this 32-column half: D[n][m], wave-private m rows
#pragma unroll
            for (int nt2 = 0; nt2 < 2; ++nt2) {
                const int nt = 2 * h + nt2;
                const s16x8 a0 = *(const s16x8*)&KT[nt * 16 + c][q * 8];
                const s16x8 a1 = *(const s16x8*)&KT[nt * 16 + c][32 + q * 8];
                const float4 dg = *(const float4*)&dgp[n0 + nt * 16 + q * 4];
#pragma unroll
                for (int mt = 0; mt < 4; ++mt) {
                    f32x4 u = {0.f, 0.f, 0.f, 0.f};
                    u = __builtin_amdgcn_mfma_f32_16x16x32_bf16(a0, P[mt][0], u, 0, 0, 0);
                    u = __builtin_amdgcn_mfma_f32_16x16x32_bf16(a1, P[mt][1], u, 0, 0, 0);
                    const float e0 = __expf(u[0] * DNRM - dg.x - stab) + EPSV;
                    const float e1 = __expf(u[1] * DNRM - dg.y - stab) + EPSV;
                    const float e2 = __expf(u[2] * DNRM - dg.z - stab) + EPSV;
                    const float e3 = __expf(u[3] * DNRM - dg.w - stab) + EPSV;
                    kn[mt] += (e0 + e1) + (e2 + e3);
                    *(short4*)&PH[(4 * w + mt) * 16 + c][nt2 * 16 + q * 4] =
                        make_short4((short)f2b(e0), (short)f2b(e1),
                                    (short)f2b(e2), (short)f2b(e3));
                }
            }
            // GEMM2 half: kv[m][d] += phi[m][n]·V^T[n][d] (wave-private PH)
            s16x8 bf[4];
#pragma unroll
            for (int dt = 0; dt < 4; ++dt)
                bf[dt] = *(const s16x8*)&VL[dt * 16 + c][h * 32 + q * 8];
#pragma unroll
            for (int mt = 0; mt < 4; ++mt) {
                const s16x8 a = *(const s16x8*)&PH[(4 * w + mt) * 16 + c][q * 8];
#pragma unroll
                for (int dt = 0; dt < 4; ++dt)
                    kva[mt][dt] = __builtin_amdgcn_mfma_f32_16x16x32_bf16(
                        a, bf[dt], kva[mt][dt], 0, 0, 0);
            }
        }
    }
    float* kvp = ws + OFF_KVP + (size_t)(bh * SPL + s) * Mv * Dv;
#pragma unroll
    for (int mt = 0; mt < 4; ++mt) {
        const int mrow = (4 * w + mt) * 16 + 4 * q;
#pragma unroll
        for (int dt = 0; dt < 4; ++dt) {
            const int dcol = dt * 16 + c;
#pragma unroll
            for (int r = 0; r < 4; ++r)
                kvp[(size_t)(mrow + r) * Dv + dcol] = kva[mt][dt][r];
        }
    }
#pragma unroll
    for (int mt = 0; mt < 4; ++mt) {
        kn[mt] += __shfl_xor(kn[mt], 16, 64);
        kn[mt] += __shfl_xor(kn[mt], 32, 64);
    }
    if (q == 0) {
        float* knp = ws + OFF_KNP + (bh * SPL + s) * Mv;
#pragma unroll
        for (int mt = 0; mt < 4; ++mt) knp[(4 * w + mt) * 16 + c] = kn[mt];
    }
}

// ---------------------------------------------------------------------------
// reduce split partials — fully coalesced: thread owns 4 consecutive floats
// of the flattened [m][d] plane; accumulates over the 16 splits.
__global__ __launch_bounds__(256) void favor_kvred(float* __restrict__ ws) {
    const int t = threadIdx.x, f = blockIdx.x, bh = blockIdx.y;
    const int flat = f * 1024 + t * 4;
    const int m = flat >> 6, d0 = flat & 63;
    float4 acc = make_float4(0.f, 0.f, 0.f, 0.f);
    for (int s = 0; s < SPL; ++s) {
        const float4 v =
            *(const float4*)&ws[OFF_KVP + ((size_t)(bh * SPL + s) << 14) + flat];
        acc.x += v.x; acc.y += v.y; acc.z += v.z; acc.w += v.w;
    }
    unsigned short* kvT = (unsigned short*)(ws + OFF_KVT);
    kvT[(bh * 64 + d0 + 0) * 256 + m] = f2b(acc.x);
    kvT[(bh * 64 + d0 + 1) * 256 + m] = f2b(acc.y);
    kvT[(bh * 64 + d0 + 2) * 256 + m] = f2b(acc.z);
    kvT[(bh * 64 + d0 + 3) * 256 + m] = f2b(acc.w);
    if (t < 16) {
        const int mm = f * 16 + t;
        float kk = 0.f;
        for (int s = 0; s < SPL; ++s)
            kk += ws[OFF_KNP + (bh * SPL + s) * Mv + mm];
        ws[OFF_KNF + bh * Mv + mm] = kk;
    }
}

// ---------------------------------------------------------------------------
// out: stage Q (+diag_q) → U = P·Q → col-max → exp → {PHT write + in-register
// norm} → PV MFMA → normalize → coalesced [D][N] store.
// R3: QT, dred and the fp32 out-tile are aliased INSIDE the PHT region.
// Sync ordering makes this safe: last QT read (GEMM_uq) and last dred read
// (dql) both precede the barrier that precedes the first PHT write; PHT reads
// (PV) precede the barrier that precedes the out-tile writes.
// LDS: 33792 (PHT region) + 3584 = 37376 B => 4 blocks/CU.
__global__ __launch_bounds__(256, 2) void favor_out(const float* __restrict__ query,
                                                    const float* __restrict__ proj,
                                                    const float* __restrict__ ws,
                                                    float* __restrict__ out) {
    __shared__ __align__(16) unsigned short PHT[64][264];  // [n][m] phi^T (aliased)
    __shared__ float npart[4][64];  // per-wave denominator partials
    __shared__ float knl[256];
    __shared__ float cw[4][64];
    __shared__ float stabl[64];
    __shared__ float dql[64];
    // aliases inside PHT region (dead before first PHT write):
    unsigned short (*QT)[72] = (unsigned short (*)[72]) & PHT[0][0];  // 9216 B
    float (*dred)[64] = (float (*)[64])((char*)&PHT[0][0] + 9216);    // 4096 B
    const int tid = threadIdx.x;
    const int w = tid >> 6, l = tid & 63, c = l & 15, q = l >> 4;
    const int g = tid >> 4, cs = tid & 15;
    const int nb = blockIdx.x, bh = blockIdx.y;
    const int n0 = nb * 64;
    const float* qp = query + (size_t)bh * Dv * Nv;
    const unsigned short* kvT =
        (const unsigned short*)(ws + OFF_KVT) + (size_t)bh * 64 * 256;

    // stage Q transposed (b64 writes) + diag_q partials
    {
        float4 qq[4];
#pragma unroll
        for (int di = 0; di < 4; ++di)
            qq[di] = *(const float4*)&qp[(4 * g + di) * Nv + n0 + 4 * cs];
#pragma unroll
        for (int j = 0; j < 4; ++j) {
            const float v0 = ((const float*)&qq[0])[j];
            const float v1 = ((const float*)&qq[1])[j];
            const float v2 = ((const float*)&qq[2])[j];
            const float v3 = ((const float*)&qq[3])[j];
            *(short4*)&QT[4 * cs + j][4 * g] =
                make_short4((short)f2b(v0), (short)f2b(v1), (short)f2b(v2),
                            (short)f2b(v3));
            dred[g][4 * cs + j] = (v0 * v0 + v1 * v1) + (v2 * v2 + v3 * v3);
        }
    }
    knl[tid] = ws[OFF_KNF + bh * Mv + tid];

    s16x8 P[4][2];
#pragma unroll
    for (int mt = 0; mt < 4; ++mt)
#pragma unroll
        for (int kc = 0; kc < 2; ++kc)
            P[mt][kc] = load_pfrag(proj, (4 * w + mt) * 16 + c, kc, q);
    __syncthreads();

    // GEMM_uq: D[m][n], wave w owns m = 64w..64w+63
    f32x4 u[4][4];
#pragma unroll
    for (int mt = 0; mt < 4; ++mt)
#pragma unroll
        for (int nt = 0; nt < 4; ++nt) u[mt][nt] = (f32x4){0.f, 0.f, 0.f, 0.f};
#pragma unroll
    for (int nt = 0; nt < 4; ++nt) {
        const s16x8 b0 = *(const s16x8*)&QT[nt * 16 + c][q * 8];
        const s16x8 b1 = *(const s16x8*)&QT[nt * 16 + c][32 + q * 8];
#pragma unroll
        for (int mt = 0; mt < 4; ++mt) {
            u[mt][nt] =
                __builtin_amdgcn_mfma_f32_16x16x32_bf16(P[mt][0], b0, u[mt][nt], 0, 0, 0);
            u[mt][nt] =
                __builtin_amdgcn_mfma_f32_16x16x32_bf16(P[mt][1], b1, u[mt][nt], 0, 0, 0);
        }
    }
    // per-column max over this wave's 64 m
#pragma unroll
    for (int nt = 0; nt < 4; ++nt) {
        float vm = -3.4e38f;
#pragma unroll
        for (int mt = 0; mt < 4; ++mt)
            vm = fmaxf(vm, fmaxf(fmaxf(u[mt][nt][0], u[mt][nt][1]),
                                 fmaxf(u[mt][nt][2], u[mt][nt][3])));
        vm = fmaxf(vm, __shfl_xor(vm, 16, 64));
        vm = fmaxf(vm, __shfl_xor(vm, 32, 64));
        if (q == 0) cw[w][nt * 16 + c] = vm;
    }
    __syncthreads();
    if (tid < 64) {
        stabl[tid] =
            fmaxf(fmaxf(cw[0][tid], cw[1][tid]), fmaxf(cw[2][tid], cw[3][tid]));
        float dsum = 0.f;
#pragma unroll
        for (int gg = 0; gg < 16; ++gg) dsum += dred[gg][tid];
        dql[tid] = dsum * 0.0625f;
    }
    __syncthreads();
    // exp → PHT (b64 writes; overwrites QT/dred aliases — safe past barrier)
    // + in-register denominator partials
#pragma unroll
    for (int nt = 0; nt < 4; ++nt) {
        const float sr = stabl[nt * 16 + c];
        const float dq = dql[nt * 16 + c];
        float np = 0.f;
#pragma unroll
        for (int mt = 0; mt < 4; ++mt) {
            const float e0 = __expf((u[mt][nt][0] - sr) * DNRM - dq) + EPSV;
            const float e1 = __expf((u[mt][nt][1] - sr) * DNRM - dq) + EPSV;
            const float e2 = __expf((u[mt][nt][2] - sr) * DNRM - dq) + EPSV;
            const float e3 = __expf((u[mt][nt][3] - sr) * DNRM - dq) + EPSV;
            const int mb = (4 * w + mt) * 16 + 4 * q;
            np += e0 * knl[mb] + e1 * knl[mb + 1] + e2 * knl[mb + 2] +
                  e3 * knl[mb + 3];
            *(short4*)&PHT[nt * 16 + c][mb] = make_short4(
                (short)f2b(e0), (short)f2b(e1), (short)f2b(e2), (short)f2b(e3));
        }
        np += __shfl_xor(np, 16, 64);
        np += __shfl_xor(np, 32, 64);
        if (q == 0) npart[w][nt * 16 + c] = np;
    }
    __syncthreads();
    // PV GEMM: wave w owns n-tile w; kvT B-frags from global (L2-hot)
    f32x4 acc[4];
#pragma unroll
    for (int dt = 0; dt < 4; ++dt) acc[dt] = (f32x4){0.f, 0.f, 0.f, 0.f};
#pragma unroll
    for (int kc = 0; kc < 8; ++kc) {
        const s16x8 a = *(const s16x8*)&PHT[w * 16 + c][kc * 32 + q * 8];
#pragma unroll
        for (int dt = 0; dt < 4; ++dt) {
            const s16x8 b =
                *(const s16x8*)&kvT[(size_t)(dt * 16 + c) * 256 + kc * 32 + q * 8];
            acc[dt] = __builtin_amdgcn_mfma_f32_16x16x32_bf16(a, b, acc[dt], 0, 0, 0);
        }
    }
    __syncthreads();  // PHT reads done; reuse as fp32 out tile [64][68]
    float* ot = (float*)&PHT[0][0];
    float rn[4];
#pragma unroll
    for (int r = 0; r < 4; ++r) {
        const int nl = w * 16 + 4 * q + r;
        rn[r] = 1.0f / ((npart[0][nl] + npart[1][nl]) +
                        (npart[2][nl] + npart[3][nl]));
    }
#pragma unroll
    for (int dt = 0; dt < 4; ++dt)
#pragma unroll
        for (int r = 0; r < 4; ++r)
            ot[(dt * 16 + c) * 68 + (w * 16 + 4 * q + r)] = acc[dt][r] * rn[r];
    __syncthreads();
    float* op = out + (size_t)bh * Dv * Nv;
    {
        const int d = tid >> 2, ng = (tid & 3) * 16;
#pragma unroll
        for (int i = 0; i < 4; ++i) {
            const float4 v = *(const float4*)&ot[d * 68 + ng + i * 4];
            *(float4*)&op[d * Nv + n0 + ng + i * 4] = v;
        }
    }
}

// ---------------------------------------------------------------------------
extern "C" void kernel_launch(void* const* d_in, const int* in_sizes, int n_in,
                              void* d_out, int out_size, void* d_ws, size_t ws_size,
                              hipStream_t stream) {
    const float* q = (const float*)d_in[0];
    const float* k = (const float*)d_in[1];
    const float* v = (const float*)d_in[2];
    const float* proj = (const float*)d_in[3];
    float* ws = (float*)d_ws;
    float* out = (float*)d_out;

    favor_kmax<<<dim3(SPL, 32), 256, 0, stream>>>(k, proj, ws);
    favor_kv<<<dim3(SPL, 32), 256, 0, stream>>>(k, v, proj, ws);
    favor_kvred<<<dim3(16, 32), 256, 0, stream>>>(ws);
    favor_out<<<dim3(Nv / 64, 32), 256, 0, stream>>>(q, proj, ws, out);
}

// Round 3
// 321.569 us; speedup vs baseline: 1.0902x; 1.0197x over previous
//
#include <hip/hip_runtime.h>

// FavorAttention (Performer FAVOR+) — B=4,H=8,D=64,N=8192,M=256, fp32 in/out.
// R5: R4's online-softmax with defer-threshold REMOVED (threshold 0 = exact).
// R4 post-mortem: the exp-part of k_phi is O(1e-7), comparable to eps=1e-6,
// so the unification max G must equal the true global max of the bf16
// products (as R3's kmax produced) — deferral inflated exp vs eps by up to
// e^8 and broke the output. With threshold 0, per-wave sigma is the true
// running max; G = max sigma = true global max; math == R3 up to fp order.

typedef short s16x8 __attribute__((ext_vector_type(8)));
typedef float f32x4 __attribute__((ext_vector_type(4)));

#define Dv 64
#define Nv 8192
#define Mv 256
#define BHv 32
#define SPL 16
#define NSPL (Nv / SPL)   // 512
#define NCH (NSPL / 64)   // 8

#define DNRM 0.3535533905932738f   // 64^-0.25
#define EPSV 1e-6f

// ws layout (float offsets)
#define OFF_SGM 0                               // [32][16][4] per-(split,wave) stab
#define OFF_SVP (OFF_SGM + BHv * SPL * 4)       // [32][16][64] V col-sum partials
#define OFF_KNP (OFF_SVP + BHv * SPL * 64)      // [32][16][256]
#define OFF_KNF (OFF_KNP + BHv * SPL * Mv)      // [32][256]
#define OFF_KVP (OFF_KNF + BHv * Mv)            // [32][16][256][64] fp32
#define OFF_KVT (OFF_KVP + BHv * SPL * Mv * Dv) // [32][64][256] bf16

__device__ __forceinline__ unsigned short f2b(float x) {
    return __builtin_bit_cast(unsigned short, (__bf16)x);
}

__device__ __forceinline__ s16x8 load_pfrag(const float* __restrict__ proj, int m,
                                            int kc, int q) {
    const float* p = proj + m * 64 + kc * 32 + q * 8;
    s16x8 r;
#pragma unroll
    for (int j = 0; j < 8; ++j) r[j] = (short)f2b(p[j]);
    return r;
}

// ---------------------------------------------------------------------------
// kv (online, exact): per chunk stage K,V (+diag_k partials, +V col-sums);
// per 32-col half: U in regs -> wave max -> rescale-if-new-max -> exp -> PH
// -> GEMM2. Per-wave sigma stored; kvred unifies with alpha = exp(sigma - G).
__global__ __launch_bounds__(256, 2) void favor_kv(const float* __restrict__ key,
                                                   const float* __restrict__ value,
                                                   const float* __restrict__ proj,
                                                   float* __restrict__ ws) {
    __shared__ __align__(16) unsigned short KT[64][72];   // [n][d]
    __shared__ __align__(16) unsigned short VL[64][72];   // [d][n]
    __shared__ __align__(16) unsigned short PH[256][40];  // [m][32n half] phi
    __shared__ __align__(16) float dred[16][64];          // diag partials [g][n]
    __shared__ __align__(16) float dgl[64];               // diag_k for chunk
    const int tid = threadIdx.x;
    const int w = tid >> 6, l = tid & 63, c = l & 15, q = l >> 4;
    const int g = tid >> 4, cs = tid & 15;
    const int s = blockIdx.x, bh = blockIdx.y;
    const float* kp = key + (size_t)bh * Dv * Nv;
    const float* vp = value + (size_t)bh * Dv * Nv;

    s16x8 P[4][2];
#pragma unroll
    for (int mt = 0; mt < 4; ++mt)
#pragma unroll
        for (int kc = 0; kc < 2; ++kc)
            P[mt][kc] = load_pfrag(proj, (4 * w + mt) * 16 + c, kc, q);

    f32x4 kva[4][4];
#pragma unroll
    for (int mt = 0; mt < 4; ++mt)
#pragma unroll
        for (int dt = 0; dt < 4; ++dt) kva[mt][dt] = (f32x4){0.f, 0.f, 0.f, 0.f};
    float kn[4] = {0.f, 0.f, 0.f, 0.f};
    float sv[4] = {0.f, 0.f, 0.f, 0.f};  // V col-sums (rows 4g..4g+3)
    float mx = -3.0e38f;                 // running true max (scaled-u), per wave

    for (int ch = 0; ch < NCH; ++ch) {
        const int n0 = s * NSPL + ch * 64;
        if (ch) __syncthreads();
        {
            float4 kk[4], vv[4];
#pragma unroll
            for (int di = 0; di < 4; ++di) {
                kk[di] = *(const float4*)&kp[(4 * g + di) * Nv + n0 + 4 * cs];
                vv[di] = *(const float4*)&vp[(4 * g + di) * Nv + n0 + 4 * cs];
            }
#pragma unroll
            for (int j = 0; j < 4; ++j) {
                const float k0 = ((const float*)&kk[0])[j];
                const float k1 = ((const float*)&kk[1])[j];
                const float k2 = ((const float*)&kk[2])[j];
                const float k3 = ((const float*)&kk[3])[j];
                *(short4*)&KT[4 * cs + j][4 * g] =
                    make_short4((short)f2b(k0), (short)f2b(k1), (short)f2b(k2),
                                (short)f2b(k3));
                dred[g][4 * cs + j] = (k0 * k0 + k1 * k1) + (k2 * k2 + k3 * k3);
            }
#pragma unroll
            for (int di = 0; di < 4; ++di) {
                *(short4*)&VL[4 * g + di][4 * cs] = make_short4(
                    (short)f2b(vv[di].x), (short)f2b(vv[di].y),
                    (short)f2b(vv[di].z), (short)f2b(vv[di].w));
                sv[di] += (vv[di].x + vv[di].y) + (vv[di].z + vv[di].w);
            }
        }
        __syncthreads();
        if (tid < 64) {
            float ds = 0.f;
#pragma unroll
            for (int gg = 0; gg < 16; ++gg) ds += dred[gg][tid];
            dgl[tid] = ds * 0.0625f;
        }
        __syncthreads();
#pragma unroll
        for (int h = 0; h < 2; ++h) {
            // GEMM1 half: u[mt][nt2] in registers (D[n][m] layout)
            f32x4 u[4][2];
#pragma unroll
            for (int nt2 = 0; nt2 < 2; ++nt2) {
                const int nt = 2 * h + nt2;
                const s16x8 a0 = *(const s16x8*)&KT[nt * 16 + c][q * 8];
                const s16x8 a1 = *(const s16x8*)&KT[nt * 16 + c][32 + q * 8];
#pragma unroll
                for (int mt = 0; mt < 4; ++mt) {
                    f32x4 t = {0.f, 0.f, 0.f, 0.f};
                    t = __builtin_amdgcn_mfma_f32_16x16x32_bf16(a0, P[mt][0], t, 0, 0, 0);
                    t = __builtin_amdgcn_mfma_f32_16x16x32_bf16(a1, P[mt][1], t, 0, 0, 0);
                    u[mt][nt2] = t;
                }
            }
            // wave max of scaled u over this half
            float cm = -3.0e38f;
#pragma unroll
            for (int mt = 0; mt < 4; ++mt)
#pragma unroll
                for (int nt2 = 0; nt2 < 2; ++nt2)
                    cm = fmaxf(cm, fmaxf(fmaxf(u[mt][nt2][0], u[mt][nt2][1]),
                                         fmaxf(u[mt][nt2][2], u[mt][nt2][3])));
            cm *= DNRM;
#pragma unroll
            for (int off = 1; off < 64; off <<= 1)
                cm = fmaxf(cm, __shfl_xor(cm, off, 64));
            if (cm > mx) {  // exact online softmax: rescale on every new max
                const float al = __expf(mx - cm);  // mx=-3e38 -> 0, kva==0 ok
#pragma unroll
                for (int mt = 0; mt < 4; ++mt) {
#pragma unroll
                    for (int dt = 0; dt < 4; ++dt) kva[mt][dt] *= al;
                    kn[mt] *= al;
                }
                mx = cm;
            }
            // exp -> PH (wave-private rows) + kn accum; e <= exp(-dg) <= 1
#pragma unroll
            for (int nt2 = 0; nt2 < 2; ++nt2) {
                const int nt = 2 * h + nt2;
                const float4 dg = *(const float4*)&dgl[nt * 16 + q * 4];
#pragma unroll
                for (int mt = 0; mt < 4; ++mt) {
                    const float e0 = __expf(u[mt][nt2][0] * DNRM - dg.x - mx);
                    const float e1 = __expf(u[mt][nt2][1] * DNRM - dg.y - mx);
                    const float e2 = __expf(u[mt][nt2][2] * DNRM - dg.z - mx);
                    const float e3 = __expf(u[mt][nt2][3] * DNRM - dg.w - mx);
                    kn[mt] += (e0 + e1) + (e2 + e3);
                    *(short4*)&PH[(4 * w + mt) * 16 + c][nt2 * 16 + q * 4] =
                        make_short4((short)f2b(e0), (short)f2b(e1),
                                    (short)f2b(e2), (short)f2b(e3));
                }
            }
            // GEMM2 half: kv[m][d] += phi[m][n]·V^T[n][d]
            s16x8 bf[4];
#pragma unroll
            for (int dt = 0; dt < 4; ++dt)
                bf[dt] = *(const s16x8*)&VL[dt * 16 + c][h * 32 + q * 8];
#pragma unroll
            for (int mt = 0; mt < 4; ++mt) {
                const s16x8 a = *(const s16x8*)&PH[(4 * w + mt) * 16 + c][q * 8];
#pragma unroll
                for (int dt = 0; dt < 4; ++dt)
                    kva[mt][dt] = __builtin_amdgcn_mfma_f32_16x16x32_bf16(
                        a, bf[dt], kva[mt][dt], 0, 0, 0);
            }
        }
    }
    // store fp32 kv partials (unscaled; sigma stored separately)
    float* kvp = ws + OFF_KVP + (size_t)(bh * SPL + s) * Mv * Dv;
#pragma unroll
    for (int mt = 0; mt < 4; ++mt) {
        const int mrow = (4 * w + mt) * 16 + 4 * q;
#pragma unroll
        for (int dt = 0; dt < 4; ++dt) {
            const int dcol = dt * 16 + c;
#pragma unroll
            for (int r = 0; r < 4; ++r)
                kvp[(size_t)(mrow + r) * Dv + dcol] = kva[mt][dt][r];
        }
    }
#pragma unroll
    for (int mt = 0; mt < 4; ++mt) {
        kn[mt] += __shfl_xor(kn[mt], 16, 64);
        kn[mt] += __shfl_xor(kn[mt], 32, 64);
    }
    if (q == 0) {
        float* knp = ws + OFF_KNP + (bh * SPL + s) * Mv;
#pragma unroll
        for (int mt = 0; mt < 4; ++mt) knp[(4 * w + mt) * 16 + c] = kn[mt];
    }
    if (l == 0) ws[OFF_SGM + (bh * SPL + s) * 4 + w] = mx;
    // V col-sum reduce (reuse dred region; its last read was the final dgl pass)
    __syncthreads();
    float* sp = &dred[0][0];  // as [64][16]
#pragma unroll
    for (int di = 0; di < 4; ++di) sp[(4 * g + di) * 16 + cs] = sv[di];
    __syncthreads();
    if (tid < 64) {
        float t2 = 0.f;
#pragma unroll
        for (int j = 0; j < 16; ++j) t2 += sp[tid * 16 + j];
        ws[OFF_SVP + (bh * SPL + s) * 64 + tid] = t2;
    }
}

// ---------------------------------------------------------------------------
// reduce split partials with per-(split,wave) rescale alpha_s=exp(sigma_s-G),
// add eps terms: kv += eps*Sum_n(v[d]); kn += eps*N. Coalesced as before.
__global__ __launch_bounds__(256) void favor_kvred(float* __restrict__ ws) {
    __shared__ float sgl[64];
    __shared__ float alph[SPL];
    __shared__ float svl[64];
    __shared__ float Gs;
    const int t = threadIdx.x, f = blockIdx.x, bh = blockIdx.y;
    const int flat = f * 1024 + t * 4;
    const int m = flat >> 6, d0 = flat & 63;
    const int wgrp = f >> 2;  // = m>>6, uniform per block
    if (t < 64) {
        const float v = ws[OFF_SGM + bh * 64 + t];
        sgl[t] = v;
        float gm = v;
#pragma unroll
        for (int off = 1; off < 64; off <<= 1)
            gm = fmaxf(gm, __shfl_xor(gm, off, 64));
        if (t == 0) Gs = gm;
    } else if (t < 128) {
        const int d = t - 64;
        float x = 0.f;
#pragma unroll
        for (int s2 = 0; s2 < SPL; ++s2)
            x += ws[OFF_SVP + (bh * SPL + s2) * 64 + d];
        svl[d] = x;
    }
    __syncthreads();
    if (t < SPL) alph[t] = __expf(sgl[t * 4 + wgrp] - Gs);
    __syncthreads();
    float4 acc = make_float4(0.f, 0.f, 0.f, 0.f);
    for (int s2 = 0; s2 < SPL; ++s2) {
        const float a = alph[s2];
        const float4 v =
            *(const float4*)&ws[OFF_KVP + ((size_t)(bh * SPL + s2) << 14) + flat];
        acc.x += a * v.x; acc.y += a * v.y; acc.z += a * v.z; acc.w += a * v.w;
    }
    acc.x += EPSV * svl[d0 + 0];
    acc.y += EPSV * svl[d0 + 1];
    acc.z += EPSV * svl[d0 + 2];
    acc.w += EPSV * svl[d0 + 3];
    unsigned short* kvT = (unsigned short*)(ws + OFF_KVT);
    kvT[(bh * 64 + d0 + 0) * 256 + m] = f2b(acc.x);
    kvT[(bh * 64 + d0 + 1) * 256 + m] = f2b(acc.y);
    kvT[(bh * 64 + d0 + 2) * 256 + m] = f2b(acc.z);
    kvT[(bh * 64 + d0 + 3) * 256 + m] = f2b(acc.w);
    if (t < 16) {
        const int mm = f * 16 + t;
        float kk = 0.f;
        for (int s2 = 0; s2 < SPL; ++s2)
            kk += alph[s2] * ws[OFF_KNP + (bh * SPL + s2) * Mv + mm];
        ws[OFF_KNF + bh * Mv + mm] = kk + EPSV * (float)Nv;
    }
}

// ---------------------------------------------------------------------------
// out: stage Q (+diag_q) → U = P·Q → col-max → exp → {PHT write + in-register
// norm} → PV MFMA → normalize → coalesced [D][N] store. (unchanged from R3)
__global__ __launch_bounds__(256, 2) void favor_out(const float* __restrict__ query,
                                                    const float* __restrict__ proj,
                                                    const float* __restrict__ ws,
                                                    float* __restrict__ out) {
    __shared__ __align__(16) unsigned short PHT[64][264];  // [n][m] phi^T (aliased)
    __shared__ float npart[4][64];  // per-wave denominator partials
    __shared__ float knl[256];
    __shared__ float cw[4][64];
    __shared__ float stabl[64];
    __shared__ float dql[64];
    // aliases inside PHT region (dead before first PHT write):
    unsigned short (*QT)[72] = (unsigned short (*)[72]) & PHT[0][0];  // 9216 B
    float (*dred)[64] = (float (*)[64])((char*)&PHT[0][0] + 9216);    // 4096 B
    const int tid = threadIdx.x;
    const int w = tid >> 6, l = tid & 63, c = l & 15, q = l >> 4;
    const int g = tid >> 4, cs = tid & 15;
    const int nb = blockIdx.x, bh = blockIdx.y;
    const int n0 = nb * 64;
    const float* qp = query + (size_t)bh * Dv * Nv;
    const unsigned short* kvT =
        (const unsigned short*)(ws + OFF_KVT) + (size_t)bh * 64 * 256;

    // stage Q transposed (b64 writes) + diag_q partials
    {
        float4 qq[4];
#pragma unroll
        for (int di = 0; di < 4; ++di)
            qq[di] = *(const float4*)&qp[(4 * g + di) * Nv + n0 + 4 * cs];
#pragma unroll
        for (int j = 0; j < 4; ++j) {
            const float v0 = ((const float*)&qq[0])[j];
            const float v1 = ((const float*)&qq[1])[j];
            const float v2 = ((const float*)&qq[2])[j];
            const float v3 = ((const float*)&qq[3])[j];
            *(short4*)&QT[4 * cs + j][4 * g] =
                make_short4((short)f2b(v0), (short)f2b(v1), (short)f2b(v2),
                            (short)f2b(v3));
            dred[g][4 * cs + j] = (v0 * v0 + v1 * v1) + (v2 * v2 + v3 * v3);
        }
    }
    knl[tid] = ws[OFF_KNF + bh * Mv + tid];

    s16x8 P[4][2];
#pragma unroll
    for (int mt = 0; mt < 4; ++mt)
#pragma unroll
        for (int kc = 0; kc < 2; ++kc)
            P[mt][kc] = load_pfrag(proj, (4 * w + mt) * 16 + c, kc, q);
    __syncthreads();

    // GEMM_uq: D[m][n], wave w owns m = 64w..64w+63
    f32x4 u[4][4];
#pragma unroll
    for (int mt = 0; mt < 4; ++mt)
#pragma unroll
        for (int nt = 0; nt < 4; ++nt) u[mt][nt] = (f32x4){0.f, 0.f, 0.f, 0.f};
#pragma unroll
    for (int nt = 0; nt < 4; ++nt) {
        const s16x8 b0 = *(const s16x8*)&QT[nt * 16 + c][q * 8];
        const s16x8 b1 = *(const s16x8*)&QT[nt * 16 + c][32 + q * 8];
#pragma unroll
        for (int mt = 0; mt < 4; ++mt) {
            u[mt][nt] =
                __builtin_amdgcn_mfma_f32_16x16x32_bf16(P[mt][0], b0, u[mt][nt], 0, 0, 0);
            u[mt][nt] =
                __builtin_amdgcn_mfma_f32_16x16x32_bf16(P[mt][1], b1, u[mt][nt], 0, 0, 0);
        }
    }
    // per-column max over this wave's 64 m
#pragma unroll
    for (int nt = 0; nt < 4; ++nt) {
        float vm = -3.4e38f;
#pragma unroll
        for (int mt = 0; mt < 4; ++mt)
            vm = fmaxf(vm, fmaxf(fmaxf(u[mt][nt][0], u[mt][nt][1]),
                                 fmaxf(u[mt][nt][2], u[mt][nt][3])));
        vm = fmaxf(vm, __shfl_xor(vm, 16, 64));
        vm = fmaxf(vm, __shfl_xor(vm, 32, 64));
        if (q == 0) cw[w][nt * 16 + c] = vm;
    }
    __syncthreads();
    if (tid < 64) {
        stabl[tid] =
            fmaxf(fmaxf(cw[0][tid], cw[1][tid]), fmaxf(cw[2][tid], cw[3][tid]));
        float dsum = 0.f;
#pragma unroll
        for (int gg = 0; gg < 16; ++gg) dsum += dred[gg][tid];
        dql[tid] = dsum * 0.0625f;
    }
    __syncthreads();
    // exp → PHT (b64 writes; overwrites QT/dred aliases — safe past barrier)
    // + in-register denominator partials
#pragma unroll
    for (int nt = 0; nt < 4; ++nt) {
        const float sr = stabl[nt * 16 + c];
        const float dq = dql[nt * 16 + c];
        float np = 0.f;
#pragma unroll
        for (int mt = 0; mt < 4; ++mt) {
            const float e0 = __expf((u[mt][nt][0] - sr) * DNRM - dq) + EPSV;
            const float e1 = __expf((u[mt][nt][1] - sr) * DNRM - dq) + EPSV;
            const float e2 = __expf((u[mt][nt][2] - sr) * DNRM - dq) + EPSV;
            const float e3 = __expf((u[mt][nt][3] - sr) * DNRM - dq) + EPSV;
            const int mb = (4 * w + mt) * 16 + 4 * q;
            np += e0 * knl[mb] + e1 * knl[mb + 1] + e2 * knl[mb + 2] +
                  e3 * knl[mb + 3];
            *(short4*)&PHT[nt * 16 + c][mb] = make_short4(
                (short)f2b(e0), (short)f2b(e1), (short)f2b(e2), (short)f2b(e3));
        }
        np += __shfl_xor(np, 16, 64);
        np += __shfl_xor(np, 32, 64);
        if (q == 0) npart[w][nt * 16 + c] = np;
    }
    __syncthreads();
    // PV GEMM: wave w owns n-tile w; kvT B-frags from global (L2-hot)
    f32x4 acc[4];
#pragma unroll
    for (int dt = 0; dt < 4; ++dt) acc[dt] = (f32x4){0.f, 0.f, 0.f, 0.f};
#pragma unroll
    for (int kc = 0; kc < 8; ++kc) {
        const s16x8 a = *(const s16x8*)&PHT[w * 16 + c][kc * 32 + q * 8];
#pragma unroll
        for (int dt = 0; dt < 4; ++dt) {
            const s16x8 b =
                *(const s16x8*)&kvT[(size_t)(dt * 16 + c) * 256 + kc * 32 + q * 8];
            acc[dt] = __builtin_amdgcn_mfma_f32_16x16x32_bf16(a, b, acc[dt], 0, 0, 0);
        }
    }
    __syncthreads();  // PHT reads done; reuse as fp32 out tile [64][68]
    float* ot = (float*)&PHT[0][0];
    float rn[4];
#pragma unroll
    for (int r = 0; r < 4; ++r) {
        const int nl = w * 16 + 4 * q + r;
        rn[r] = 1.0f / ((npart[0][nl] + npart[1][nl]) +
                        (npart[2][nl] + npart[3][nl]));
    }
#pragma unroll
    for (int dt = 0; dt < 4; ++dt)
#pragma unroll
        for (int r = 0; r < 4; ++r)
            ot[(dt * 16 + c) * 68 + (w * 16 + 4 * q + r)] = acc[dt][r] * rn[r];
    __syncthreads();
    float* op = out + (size_t)bh * Dv * Nv;
    {
        const int d = tid >> 2, ng = (tid & 3) * 16;
#pragma unroll
        for (int i = 0; i < 4; ++i) {
            const float4 v = *(const float4*)&ot[d * 68 + ng + i * 4];
            *(float4*)&op[d * Nv + n0 + ng + i * 4] = v;
        }
    }
}

// ---------------------------------------------------------------------------
extern "C" void kernel_launch(void* const* d_in, const int* in_sizes, int n_in,
                              void* d_out, int out_size, void* d_ws, size_t ws_size,
                              hipStream_t stream) {
    const float* q = (const float*)d_in[0];
    const float* k = (const float*)d_in[1];
    const float* v = (const float*)d_in[2];
    const float* proj = (const float*)d_in[3];
    float* ws = (float*)d_ws;
    float* out = (float*)d_out;

    favor_kv<<<dim3(SPL, 32), 256, 0, stream>>>(k, v, proj, ws);
    favor_kvred<<<dim3(16, 32), 256, 0, stream>>>(ws);
    favor_out<<<dim3(Nv / 64, 32), 256, 0, stream>>>(q, proj, ws, out);
}